// Round 1
// baseline (97.912 us; speedup 1.0000x reference)
//
#include <hip/hip_runtime.h>
#include <math.h>

// Problem constants (from reference): B=2048, I=512, O=512
#define B_DIM 2048
#define I_DIM 512
#define O_DIM 512

constexpr int R_ROWS  = 16;              // b-rows per block (was 8: halves ab L2 demand to ~32 B/cy/CU)
constexpr int W_CHUNK = 4;               // i-chunks (threadIdx.y)
constexpr int CHUNK   = I_DIM / W_CHUNK; // 128 i per chunk
constexpr int KP      = CHUNK / 2;       // 64 i-pair rows per chunk

// ws layout: ab4 at base (2 MB). Benign ab prefetch overruns (<=32 KB past
// row 255) land in the 256 MB workspace slack.

// ---------------------------------------------------------------------------
// Setup kernel: precompute the affine ab table only (xt retile dropped — x is
// now staged per-block into LDS by the main kernel).
//   factor[b,i,o] = 1 - w*(1 - xnor) = a[i,o] + bcoef[i,o]*x[b,i]
//   a = 1 - w*s ; bcoef = w*(2s - 1)
// ab layout: float4 (a0,a1,b0,b1) at ab4[k*O_DIM+o], k = i/2.
// ---------------------------------------------------------------------------
__global__ __launch_bounds__(256) void setup_kernel(
    const float* __restrict__ w_logits,
    const float* __restrict__ s_logits,
    float4* __restrict__ ab4)
{
    int t  = blockIdx.x * 256 + threadIdx.x;  // 0 .. 131071
    int o  = t & (O_DIM - 1);
    int k  = t >> 9;                          // i-pair index, 0..255
    int i0 = 2 * k;

    float zw0 = w_logits[(i0 + 0) * O_DIM + o];
    float zs0 = s_logits[(i0 + 0) * O_DIM + o];
    float zw1 = w_logits[(i0 + 1) * O_DIM + o];
    float zs1 = s_logits[(i0 + 1) * O_DIM + o];

    float w0 = 1.0f / (1.0f + expf(-zw0));
    float s0 = 1.0f / (1.0f + expf(-zs0));
    float w1 = 1.0f / (1.0f + expf(-zw1));
    float s1 = 1.0f / (1.0f + expf(-zs1));

    float4 v;
    v.x = fmaf(-w0, s0, 1.0f);        // a0
    v.y = fmaf(-w1, s1, 1.0f);        // a1
    v.z = w0 * (2.0f * s0 - 1.0f);    // b0
    v.w = w1 * (2.0f * s1 - 1.0f);    // b1
    ab4[k * O_DIM + o] = v;
}

// ---------------------------------------------------------------------------
// Main product kernel. Block (256,4): lanes = o (coalesced ab stream),
// threadIdx.y = i-chunk. Grid (2,128) = 256 blocks = 1 block/CU, 16 waves/CU
// (4/SIMD). R_ROWS=16 rows per thread halves the per-CU ab L2 demand vs the
// previous 8-row version (64 -> 32 B/cycle/CU, under the ~56 B/cy ceiling).
// x for the block's 16 rows is staged ONCE into LDS (32 KB) and read back by
// wave-uniform broadcast ds_read_b128 — this removes the SGPR-slab SMEM
// double-buffer and its out-of-order lgkmcnt(0) drain hazard entirely.
// __launch_bounds__(1024,4) -> 128 VGPR budget: no forced-64-VGPR pressure.
// ---------------------------------------------------------------------------
__global__ __launch_bounds__(1024, 4) void fuzzy_main(
    const float* __restrict__ x,       // (B, I) fp32, read directly
    const float4* __restrict__ ab4,
    float* __restrict__ out)
{
    // 64 KB LDS, overlaid: x-tile (32 KB) during the product loop, then the
    // 4-chunk combine buffer (64 KB) after a barrier.
    __shared__ __align__(16) unsigned char sh_raw[W_CHUNK * R_ROWS * 256 * 4];
    float4 (*xs4)[CHUNK]        = reinterpret_cast<float4(*)[CHUNK]>(sh_raw);        // [16][128]
    float  (*part)[R_ROWS][256] = reinterpret_cast<float(*)[R_ROWS][256]>(sh_raw);   // [4][16][256]

    const int o_l = threadIdx.x;              // 0..255
    const int o   = blockIdx.x * 256 + o_l;
    const int y   = __builtin_amdgcn_readfirstlane((int)threadIdx.y); // 0..3, wave-uniform
    const int g   = blockIdx.y;               // b-group (16 rows)
    const int b0  = g * R_ROWS;
    const int kbase = y * KP;                 // this chunk's first ab pair-row

    // Lane-varying base + uniform row offset -> saddr-form global loads.
    const float4* ab_o = ab4 + o;

    // Issue the ab pipeline prime FIRST so it overlaps the x staging.
    float4 pA0 = ab_o[(size_t)(kbase + 0) * O_DIM];
    float4 pA1 = ab_o[(size_t)(kbase + 1) * O_DIM];
    float4 pB0 = ab_o[(size_t)(kbase + 2) * O_DIM];
    float4 pB1 = ab_o[(size_t)(kbase + 3) * O_DIM];

    // Stage x tile: 16 rows x 512 f = 2048 float4; 1024 threads x 2, fully
    // coalesced (each pass is a contiguous 16 KB per 1024 threads).
    {
        const float4* x4 = (const float4*)x;
        const int tid = threadIdx.y * 256 + o_l;  // 0..1023
#pragma unroll
        for (int p = 0; p < 2; ++p) {
            int fidx = p * 1024 + tid;            // 0..2047
            int r = fidx >> 7;                    // row 0..15
            int q = fidx & (CHUNK - 1);           // quad 0..127
            xs4[r][q] = x4[(size_t)(b0 + r) * (I_DIM / 4) + q];
        }
    }
    __syncthreads();

    float acc[R_ROWS];
#pragma unroll
    for (int r = 0; r < R_ROWS; ++r) acc[r] = 1.0f;

    for (int k = 0; k < KP; k += 4) {         // 16 outer iters, 2 stages each
        const int qA = (kbase + k) >> 1;      // x quad for stage A (uniform)
        // ---- stage A: pair-rows kbase+k, +k+1 ----
        {
            float4 c0 = pA0, c1 = pA1;
            // Prefetch 1 full iter (~512 issue-cycles) ahead; final iters
            // overrun ab4 by <=32 KB -> inside the 256 MB ws.
            pA0 = ab_o[(size_t)(kbase + k + 4) * O_DIM];
            pA1 = ab_o[(size_t)(kbase + k + 5) * O_DIM];
#pragma unroll
            for (int r = 0; r < R_ROWS; ++r) {
                float4 xv = xs4[r][qA];       // wave-uniform broadcast ds_read_b128
                float f0 = fmaf(c0.z, xv.x, c0.x);
                float f1 = fmaf(c0.w, xv.y, c0.y);
                float f2 = fmaf(c1.z, xv.z, c1.x);
                float f3 = fmaf(c1.w, xv.w, c1.y);
                acc[r] *= (f0 * f2) * (f1 * f3);
            }
        }
        // ---- stage B: pair-rows kbase+k+2, +k+3 ----
        {
            float4 c0 = pB0, c1 = pB1;
            pB0 = ab_o[(size_t)(kbase + k + 6) * O_DIM];
            pB1 = ab_o[(size_t)(kbase + k + 7) * O_DIM];
#pragma unroll
            for (int r = 0; r < R_ROWS; ++r) {
                float4 xv = xs4[r][qA + 1];
                float f0 = fmaf(c0.z, xv.x, c0.x);
                float f1 = fmaf(c0.w, xv.y, c0.y);
                float f2 = fmaf(c1.z, xv.z, c1.x);
                float f3 = fmaf(c1.w, xv.w, c1.y);
                acc[r] *= (f0 * f2) * (f1 * f3);
            }
        }
    }

    // Combine the 4 i-chunk partials per (row, o) via LDS (overlays x-tile;
    // barrier guarantees every wave is done reading xs4 first).
    __syncthreads();
#pragma unroll
    for (int r = 0; r < R_ROWS; ++r)
        part[y][r][o_l] = acc[r];
    __syncthreads();
    // 16 rows / 4 y-groups -> 4 rows per thread; stride-1 in o -> coalesced.
#pragma unroll
    for (int rr = 0; rr < 4; ++rr) {
        int r = y * 4 + rr;
        float v = part[0][r][o_l] * part[1][r][o_l]
                * part[2][r][o_l] * part[3][r][o_l];
        out[(size_t)(b0 + r) * O_DIM + o] = v;
    }
}

extern "C" void kernel_launch(void* const* d_in, const int* in_sizes, int n_in,
                              void* d_out, int out_size, void* d_ws, size_t ws_size,
                              hipStream_t stream) {
    const float* x        = (const float*)d_in[0];   // (B, I) fp32
    const float* w_logits = (const float*)d_in[1];   // (I, O) fp32
    const float* s_logits = (const float*)d_in[2];   // (I, O) fp32
    float* out = (float*)d_out;                      // (B, O) fp32
    float4* ab4 = (float4*)d_ws;                     // [0, 2MB) + prefetch slack

    // Setup: ab table only (512 blocks).
    setup_kernel<<<dim3(512), dim3(256), 0, stream>>>(w_logits, s_logits, ab4);

    // Grid (O/256, B/16) = (2, 128) = 256 blocks of (256,4)=1024 threads.
    fuzzy_main<<<dim3(O_DIM / 256, B_DIM / R_ROWS), dim3(256, W_CHUNK), 0, stream>>>(
        x, ab4, out);
}